// Round 8
// baseline (438.169 us; speedup 1.0000x reference)
//
#include <hip/hip_runtime.h>
#include <math.h>

// LePE attention (CSWin vertical split) — fp16 single-precision MFMA, v3.
// R7 post-mortem: 255 µs rocprof, VALU-bound (47%) at 2 waves/SIMD, conflicts
// 3e7. v3: (a) fp16 operands everywhere (1 MFMA term instead of 3, half the
// pack VALU; ~2^-11 accuracy beats v2's bf16-lepe-limited 0.0156);
// (b) LDS 152K -> 64.8K => 2 blocks/CU, 4 waves/SIMD; (c) lepe computed
// on-the-fly by consumer lanes from fp16 V in LDS (conv weights in LDS);
// (d) defer-max skips rescale when __all(tmax-m<=8); (e) V pad zeroing fixed
// to exact swizzled physical slots (v2 left 408..415 garbage).

#define BATCH 16
#define HH 56
#define WW 56
#define WSP 7
#define NHEAD 8
#define HD 32
#define DIMC 256
#define NTOK 3136
#define S 392
#define SPAD 416          // keys padded to 13 chunks of 32
#define NCH 13
#define QT 25             // q tiles of 16 (covers 400)
#define QSCALE 0.17677669529663687f

typedef __attribute__((ext_vector_type(8))) _Float16 half8;
typedef __attribute__((ext_vector_type(4))) _Float16 half4;
typedef __attribute__((ext_vector_type(4))) float f32x4;

#define MFMA(A, B, C) __builtin_amdgcn_mfma_f32_16x16x32_f16((A), (B), (C), 0, 0, 0)

__global__ __launch_bounds__(512, 4)
void lepe_attn_f16(const float* __restrict__ qkv,
                   const float* __restrict__ conv_w,
                   const float* __restrict__ conv_b,
                   float* __restrict__ out)
{
    // K rows (32 halves = 64B): 4 slots of 16B, slot' = slot ^ ((t>>1)&3)
    // V rows (SPAD halves): 16B granule s' = s ^ ((d>>1)&3) within 32-key chunk
    __shared__ _Float16 K_s[SPAD * HD];    // [key][dim]     26624 B
    __shared__ _Float16 V_s[HD * SPAD];    // [dim][key]     26624 B
    __shared__ _Float16 P_s[8][16 * 40];   // per-wave P     10240 B
    __shared__ float    cw_s[HD * 9];      // conv w (head)   1152 B
    __shared__ float    cb_s[HD];          // conv b           128 B

    const int tid  = threadIdx.x;
    const int lane = tid & 63;
    const int wv   = tid >> 6;
    const int ql   = lane & 15;          // q column / A-frag row
    const int g    = lane >> 4;          // k/dim sub-group
    const int slot = ((g ^ ((ql >> 1) & 3)) << 3);  // swizzled 16B slot (halves)
    const int bid  = blockIdx.x;
    const int head = bid & 7;
    const int gw   = bid >> 3;
    const int b    = gw >> 3;
    const int wi   = gw & 7;
    const int coff = head * HD;

    const float* qbase = qkv + (size_t)b * NTOK * DIMC;
    const float* kbase = qkv + (size_t)(BATCH + b) * NTOK * DIMC;
    const float* vbase = qkv + (size_t)(2 * BATCH + b) * NTOK * DIMC;

    // ---- stage conv weights for this head
    for (int j = tid; j < HD * 9; j += 512) cw_s[j] = conv_w[coff * 9 + j];
    if (tid < HD) cb_s[tid] = conv_b[coff + tid];

    // ---- zero pads at their exact (swizzled) physical slots; disjoint from
    //      staging writes, so no barrier needed before staging.
    for (int j = tid; j < 768; j += 512) {
        K_s[(392 + (j >> 5)) * HD + (j & 31)] = (_Float16)0.f;
        const int d = j & 31, ko = j >> 5;
        V_s[d * SPAD + ((392 + ko) ^ (((d >> 1) & 3) << 3))] = (_Float16)0.f;
    }

    // ---- stage K (row-major, slot-swizzled) and V (transposed, swizzled)
    for (int i = tid; i < S * 8; i += 512) {
        const int t  = i >> 3;
        const int f4 = i & 7;
        const int y  = t / WSP, x = t - y * WSP;
        const int n  = y * WW + wi * WSP + x;
        const float4 kk = *(const float4*)(kbase + (size_t)n * DIMC + coff + f4 * 4);
        const float4 vv = *(const float4*)(vbase + (size_t)n * DIMC + coff + f4 * 4);
        half4 kh;
        kh[0] = (_Float16)kk.x; kh[1] = (_Float16)kk.y;
        kh[2] = (_Float16)kk.z; kh[3] = (_Float16)kk.w;
        *(half4*)&K_s[t * HD + ((f4 << 2) ^ (((t >> 1) & 3) << 3))] = kh;
#pragma unroll
        for (int j = 0; j < 4; ++j) {
            const int d = f4 * 4 + j;
            V_s[d * SPAD + (t ^ (((d >> 1) & 3) << 3))] =
                (_Float16)((const float*)&vv)[j];
        }
    }
    __syncthreads();

    // ---- main flash loop: wave wv handles q-tiles {wv, wv+8, ...}
    _Float16* Ph = &P_s[wv][0];

    for (int qt = wv; qt < QT; qt += 8) {
        const int qtok = qt * 16 + ql;
        const int qc   = (qtok < S) ? qtok : (S - 1);
        const int qy   = qc / WSP, qx = qc - qy * WSP;
        const float* qp = qbase + (size_t)(qy * WW + wi * WSP + qx) * DIMC + coff + g * 8;
        const float4 qa = *(const float4*)qp;
        const float4 qb = *(const float4*)(qp + 4);
        half8 Qf;
        Qf[0] = (_Float16)(qa.x * QSCALE); Qf[1] = (_Float16)(qa.y * QSCALE);
        Qf[2] = (_Float16)(qa.z * QSCALE); Qf[3] = (_Float16)(qa.w * QSCALE);
        Qf[4] = (_Float16)(qb.x * QSCALE); Qf[5] = (_Float16)(qb.y * QSCALE);
        Qf[6] = (_Float16)(qb.z * QSCALE); Qf[7] = (_Float16)(qb.w * QSCALE);

        f32x4 O0 = {0.f, 0.f, 0.f, 0.f};
        f32x4 O1 = {0.f, 0.f, 0.f, 0.f};
        float m = -INFINITY, lsum = 0.f;

        for (int c = 0; c < NCH; ++c) {
            const half8 Ka = *(const half8*)&K_s[(c * 32 + ql) * HD + slot];
            const half8 Kb = *(const half8*)&K_s[(c * 32 + 16 + ql) * HD + slot];
            f32x4 sa = {0.f, 0.f, 0.f, 0.f};
            f32x4 sb = {0.f, 0.f, 0.f, 0.f};
            sa = MFMA(Ka, Qf, sa);
            sb = MFMA(Kb, Qf, sb);

            if (c == NCH - 1) {   // mask keys >= 392 (key = c*32 (+16) + 4g + r)
#pragma unroll
                for (int r = 0; r < 4; ++r) {
                    if (c * 32 + 4 * g + r >= S)      sa[r] = -1e30f;
                    if (c * 32 + 16 + 4 * g + r >= S) sb[r] = -1e30f;
                }
            }

            float tmax = fmaxf(fmaxf(fmaxf(sa[0], sa[1]), fmaxf(sa[2], sa[3])),
                               fmaxf(fmaxf(sb[0], sb[1]), fmaxf(sb[2], sb[3])));
            tmax = fmaxf(tmax, __shfl_xor(tmax, 16));
            tmax = fmaxf(tmax, __shfl_xor(tmax, 32));

            // defer-max: rescale only when some q-row grew by > 8
            if (!__all(tmax - m <= 8.0f)) {
                const float mnew = fmaxf(m, tmax);
                const float corr = __expf(m - mnew);   // first chunk: exp(-inf)=0
                m = mnew;
                lsum *= corr;
#pragma unroll
                for (int r = 0; r < 4; ++r) { O0[r] *= corr; O1[r] *= corr; }
            }

            float pa[4], pb[4];
#pragma unroll
            for (int r = 0; r < 4; ++r) {
                pa[r] = __expf(sa[r] - m);        // bounded by e^8
                pb[r] = __expf(sb[r] - m);
            }
            lsum += ((pa[0] + pa[1]) + (pa[2] + pa[3])) +
                    ((pb[0] + pb[1]) + (pb[2] + pb[3]));

            half4 wa, wb;
#pragma unroll
            for (int r = 0; r < 4; ++r) {
                wa[r] = (_Float16)pa[r];
                wb[r] = (_Float16)pb[r];
            }
            *(half4*)&Ph[ql * 40 + 4 * g]      = wa;   // tile-a keys 4g..4g+3
            *(half4*)&Ph[ql * 40 + 16 + 4 * g] = wb;   // tile-b keys 16+4g..+3

            const half8 Pf = *(const half8*)&Ph[ql * 40 + 8 * g];
            const half8 V0 = *(const half8*)&V_s[ql * SPAD + c * 32 + slot];
            const half8 V1 = *(const half8*)&V_s[(16 + ql) * SPAD + c * 32 + slot];
            O0 = MFMA(V0, Pf, O0);
            O1 = MFMA(V1, Pf, O1);
        }

        lsum += __shfl_xor(lsum, 16);
        lsum += __shfl_xor(lsum, 32);
        const float inv = 1.f / lsum;

        if (qtok < S) {
            // ---- LePE on the fly: depthwise 3x3 (window-local zero pad) for
            //      this lane's 8 output channels, from fp16 V in LDS.
            float lp[8];
#pragma unroll
            for (int jj = 0; jj < 4; ++jj) {
                lp[jj]     = cb_s[4 * g + jj];
                lp[4 + jj] = cb_s[16 + 4 * g + jj];
            }
#pragma unroll
            for (int dy = -1; dy <= 1; ++dy) {
                const int yy = qy + dy;
                if (yy < 0 || yy >= HH) continue;
#pragma unroll
                for (int dx = -1; dx <= 1; ++dx) {
                    const int xx = qx + dx;
                    if (xx < 0 || xx >= WSP) continue;
                    const int t  = yy * WSP + xx;
                    const int kt = (dy + 1) * 3 + (dx + 1);
#pragma unroll
                    for (int jj = 0; jj < 8; ++jj) {
                        const int d = (jj < 4) ? (4 * g + jj) : (16 + 4 * g + (jj - 4));
                        lp[jj] += cw_s[d * 9 + kt] *
                                  (float)V_s[d * SPAD + (t ^ (((d >> 1) & 3) << 3))];
                    }
                }
            }
            float* op = out + ((size_t)b * NTOK + qy * WW + wi * WSP + qx) * DIMC + coff;
            float4 o0v, o1v;
            o0v.x = O0[0] * inv + lp[0]; o0v.y = O0[1] * inv + lp[1];
            o0v.z = O0[2] * inv + lp[2]; o0v.w = O0[3] * inv + lp[3];
            o1v.x = O1[0] * inv + lp[4]; o1v.y = O1[1] * inv + lp[5];
            o1v.z = O1[2] * inv + lp[6]; o1v.w = O1[3] * inv + lp[7];
            *(float4*)(op + 4 * g)      = o0v;
            *(float4*)(op + 16 + 4 * g) = o1v;
        }
    }
}

extern "C" void kernel_launch(void* const* d_in, const int* in_sizes, int n_in,
                              void* d_out, int out_size, void* d_ws, size_t ws_size,
                              hipStream_t stream)
{
    const float* qkv    = (const float*)d_in[0];
    const float* conv_w = (const float*)d_in[1];
    const float* conv_b = (const float*)d_in[2];
    float* out = (float*)d_out;

    dim3 grid(BATCH * 8 * NHEAD);   // 1024 blocks: (window, head)
    dim3 block(512);                // 8 waves; 2 blocks/CU -> 4 waves/SIMD
    lepe_attn_f16<<<grid, block, 0, stream>>>(qkv, conv_w, conv_b, out);
}

// Round 9
// 346.168 us; speedup vs baseline: 1.2658x; 1.2658x over previous
//
#include <hip/hip_runtime.h>
#include <math.h>

// LePE attention (CSWin vertical split) — fp16 MFMA, v4.
// R8 post-mortem: v3 (launch_bounds(512,4)) exploded HBM traffic 128->907 MB
// with both pipes idle — suspected register-allocator squeeze to 64 VGPR =>
// scratch spills in the flash loop. v4: relax to __launch_bounds__(512,2)
// (2 blocks/CU still available via LDS=65KB if VGPR<=128), plus Q-fragment
// software prefetch across q-tiles. Everything else identical to v3
// (fp16 operands, swizzled K/V LDS, on-the-fly LePE, defer-max).

#define BATCH 16
#define HH 56
#define WW 56
#define WSP 7
#define NHEAD 8
#define HD 32
#define DIMC 256
#define NTOK 3136
#define S 392
#define SPAD 416          // keys padded to 13 chunks of 32
#define NCH 13
#define QT 25             // q tiles of 16 (covers 400)
#define QSCALE 0.17677669529663687f

typedef __attribute__((ext_vector_type(8))) _Float16 half8;
typedef __attribute__((ext_vector_type(4))) _Float16 half4;
typedef __attribute__((ext_vector_type(4))) float f32x4;

#define MFMA(A, B, C) __builtin_amdgcn_mfma_f32_16x16x32_f16((A), (B), (C), 0, 0, 0)

__global__ __launch_bounds__(512, 2)
void lepe_attn_f16(const float* __restrict__ qkv,
                   const float* __restrict__ conv_w,
                   const float* __restrict__ conv_b,
                   float* __restrict__ out)
{
    // K rows (32 halves = 64B): 4 slots of 16B, slot' = slot ^ ((t>>1)&3)
    // V rows (SPAD halves): 16B granule s' = s ^ ((d>>1)&3) within 32-key chunk
    __shared__ _Float16 K_s[SPAD * HD];    // [key][dim]     26624 B
    __shared__ _Float16 V_s[HD * SPAD];    // [dim][key]     26624 B
    __shared__ _Float16 P_s[8][16 * 40];   // per-wave P     10240 B
    __shared__ float    cw_s[HD * 9];      // conv w (head)   1152 B
    __shared__ float    cb_s[HD];          // conv b           128 B

    const int tid  = threadIdx.x;
    const int lane = tid & 63;
    const int wv   = tid >> 6;
    const int ql   = lane & 15;          // q column / A-frag row
    const int g    = lane >> 4;          // k/dim sub-group
    const int slot = ((g ^ ((ql >> 1) & 3)) << 3);  // swizzled 16B slot (halves)
    const int bid  = blockIdx.x;
    const int head = bid & 7;
    const int gw   = bid >> 3;
    const int b    = gw >> 3;
    const int wi   = gw & 7;
    const int coff = head * HD;

    const float* qbase = qkv + (size_t)b * NTOK * DIMC;
    const float* kbase = qkv + (size_t)(BATCH + b) * NTOK * DIMC;
    const float* vbase = qkv + (size_t)(2 * BATCH + b) * NTOK * DIMC;

    // ---- stage conv weights for this head
    for (int j = tid; j < HD * 9; j += 512) cw_s[j] = conv_w[coff * 9 + j];
    if (tid < HD) cb_s[tid] = conv_b[coff + tid];

    // ---- zero pads at exact swizzled physical slots (V must be finite-zero
    //      under P=0; K pads produce masked rows so garbage would be OK, but
    //      zero both for safety). Disjoint from staging writes.
    for (int j = tid; j < 768; j += 512) {
        K_s[(392 + (j >> 5)) * HD + (j & 31)] = (_Float16)0.f;
        const int d = j & 31, ko = j >> 5;
        V_s[d * SPAD + ((392 + ko) ^ (((d >> 1) & 3) << 3))] = (_Float16)0.f;
    }

    // ---- stage K (row-major, slot-swizzled) and V (transposed, swizzled)
    for (int i = tid; i < S * 8; i += 512) {
        const int t  = i >> 3;
        const int f4 = i & 7;
        const int y  = t / WSP, x = t - y * WSP;
        const int n  = y * WW + wi * WSP + x;
        const float4 kk = *(const float4*)(kbase + (size_t)n * DIMC + coff + f4 * 4);
        const float4 vv = *(const float4*)(vbase + (size_t)n * DIMC + coff + f4 * 4);
        half4 kh;
        kh[0] = (_Float16)kk.x; kh[1] = (_Float16)kk.y;
        kh[2] = (_Float16)kk.z; kh[3] = (_Float16)kk.w;
        *(half4*)&K_s[t * HD + ((f4 << 2) ^ (((t >> 1) & 3) << 3))] = kh;
#pragma unroll
        for (int j = 0; j < 4; ++j) {
            const int d = f4 * 4 + j;
            V_s[d * SPAD + (t ^ (((d >> 1) & 3) << 3))] =
                (_Float16)((const float*)&vv)[j];
        }
    }
    __syncthreads();

    // ---- main flash loop: wave wv handles q-tiles {wv, wv+8, ...}
    _Float16* Ph = &P_s[wv][0];

    // Q prefetch pipeline (depth 1): issue tile qt+8's load before computing qt
    float4 qa, qb;
    {
        const int qtok0 = wv * 16 + ql;
        const int qc0   = (qtok0 < S) ? qtok0 : (S - 1);
        const int qy0   = qc0 / WSP, qx0 = qc0 - qy0 * WSP;
        const float* qp = qbase + (size_t)(qy0 * WW + wi * WSP + qx0) * DIMC + coff + g * 8;
        qa = *(const float4*)qp;
        qb = *(const float4*)(qp + 4);
    }

    for (int qt = wv; qt < QT; qt += 8) {
        half8 Qf;
        Qf[0] = (_Float16)(qa.x * QSCALE); Qf[1] = (_Float16)(qa.y * QSCALE);
        Qf[2] = (_Float16)(qa.z * QSCALE); Qf[3] = (_Float16)(qa.w * QSCALE);
        Qf[4] = (_Float16)(qb.x * QSCALE); Qf[5] = (_Float16)(qb.y * QSCALE);
        Qf[6] = (_Float16)(qb.z * QSCALE); Qf[7] = (_Float16)(qb.w * QSCALE);

        if (qt + 8 < QT) {   // issue next tile's Q load early (latency hidden)
            const int qtokn = (qt + 8) * 16 + ql;
            const int qcn   = (qtokn < S) ? qtokn : (S - 1);
            const int qyn   = qcn / WSP, qxn = qcn - qyn * WSP;
            const float* np = qbase + (size_t)(qyn * WW + wi * WSP + qxn) * DIMC + coff + g * 8;
            qa = *(const float4*)np;
            qb = *(const float4*)(np + 4);
        }

        const int qtok = qt * 16 + ql;
        const int qc   = (qtok < S) ? qtok : (S - 1);
        const int qy   = qc / WSP, qx = qc - qy * WSP;

        f32x4 O0 = {0.f, 0.f, 0.f, 0.f};
        f32x4 O1 = {0.f, 0.f, 0.f, 0.f};
        float m = -INFINITY, lsum = 0.f;

        for (int c = 0; c < NCH; ++c) {
            const half8 Ka = *(const half8*)&K_s[(c * 32 + ql) * HD + slot];
            const half8 Kb = *(const half8*)&K_s[(c * 32 + 16 + ql) * HD + slot];
            f32x4 sa = {0.f, 0.f, 0.f, 0.f};
            f32x4 sb = {0.f, 0.f, 0.f, 0.f};
            sa = MFMA(Ka, Qf, sa);
            sb = MFMA(Kb, Qf, sb);

            if (c == NCH - 1) {   // mask keys >= 392 (key = c*32 (+16) + 4g + r)
#pragma unroll
                for (int r = 0; r < 4; ++r) {
                    if (c * 32 + 4 * g + r >= S)      sa[r] = -1e30f;
                    if (c * 32 + 16 + 4 * g + r >= S) sb[r] = -1e30f;
                }
            }

            float tmax = fmaxf(fmaxf(fmaxf(sa[0], sa[1]), fmaxf(sa[2], sa[3])),
                               fmaxf(fmaxf(sb[0], sb[1]), fmaxf(sb[2], sb[3])));
            tmax = fmaxf(tmax, __shfl_xor(tmax, 16));
            tmax = fmaxf(tmax, __shfl_xor(tmax, 32));

            // defer-max: rescale only when some q-row grew by > 8
            if (!__all(tmax - m <= 8.0f)) {
                const float mnew = fmaxf(m, tmax);
                const float corr = __expf(m - mnew);   // first chunk: exp(-inf)=0
                m = mnew;
                lsum *= corr;
#pragma unroll
                for (int r = 0; r < 4; ++r) { O0[r] *= corr; O1[r] *= corr; }
            }

            float pa[4], pb[4];
#pragma unroll
            for (int r = 0; r < 4; ++r) {
                pa[r] = __expf(sa[r] - m);        // bounded by e^8
                pb[r] = __expf(sb[r] - m);
            }
            lsum += ((pa[0] + pa[1]) + (pa[2] + pa[3])) +
                    ((pb[0] + pb[1]) + (pb[2] + pb[3]));

            half4 wa, wb;
#pragma unroll
            for (int r = 0; r < 4; ++r) {
                wa[r] = (_Float16)pa[r];
                wb[r] = (_Float16)pb[r];
            }
            *(half4*)&Ph[ql * 40 + 4 * g]      = wa;   // tile-a keys 4g..4g+3
            *(half4*)&Ph[ql * 40 + 16 + 4 * g] = wb;   // tile-b keys 16+4g..+3

            const half8 Pf = *(const half8*)&Ph[ql * 40 + 8 * g];
            const half8 V0 = *(const half8*)&V_s[ql * SPAD + c * 32 + slot];
            const half8 V1 = *(const half8*)&V_s[(16 + ql) * SPAD + c * 32 + slot];
            O0 = MFMA(V0, Pf, O0);
            O1 = MFMA(V1, Pf, O1);
        }

        lsum += __shfl_xor(lsum, 16);
        lsum += __shfl_xor(lsum, 32);
        const float inv = 1.f / lsum;

        if (qtok < S) {
            // ---- LePE on the fly: depthwise 3x3 (window-local zero pad) for
            //      this lane's 8 output channels, from fp16 V in LDS.
            float lp[8];
#pragma unroll
            for (int jj = 0; jj < 4; ++jj) {
                lp[jj]     = cb_s[4 * g + jj];
                lp[4 + jj] = cb_s[16 + 4 * g + jj];
            }
#pragma unroll
            for (int dy = -1; dy <= 1; ++dy) {
                const int yy = qy + dy;
                if (yy < 0 || yy >= HH) continue;
#pragma unroll
                for (int dx = -1; dx <= 1; ++dx) {
                    const int xx = qx + dx;
                    if (xx < 0 || xx >= WSP) continue;
                    const int t  = yy * WSP + xx;
                    const int kt = (dy + 1) * 3 + (dx + 1);
#pragma unroll
                    for (int jj = 0; jj < 8; ++jj) {
                        const int d = (jj < 4) ? (4 * g + jj) : (16 + 4 * g + (jj - 4));
                        lp[jj] += cw_s[d * 9 + kt] *
                                  (float)V_s[d * SPAD + (t ^ (((d >> 1) & 3) << 3))];
                    }
                }
            }
            float* op = out + ((size_t)b * NTOK + qy * WW + wi * WSP + qx) * DIMC + coff;
            float4 o0v, o1v;
            o0v.x = O0[0] * inv + lp[0]; o0v.y = O0[1] * inv + lp[1];
            o0v.z = O0[2] * inv + lp[2]; o0v.w = O0[3] * inv + lp[3];
            o1v.x = O1[0] * inv + lp[4]; o1v.y = O1[1] * inv + lp[5];
            o1v.z = O1[2] * inv + lp[6]; o1v.w = O1[3] * inv + lp[7];
            *(float4*)(op + 4 * g)      = o0v;
            *(float4*)(op + 16 + 4 * g) = o1v;
        }
    }
}

extern "C" void kernel_launch(void* const* d_in, const int* in_sizes, int n_in,
                              void* d_out, int out_size, void* d_ws, size_t ws_size,
                              hipStream_t stream)
{
    const float* qkv    = (const float*)d_in[0];
    const float* conv_w = (const float*)d_in[1];
    const float* conv_b = (const float*)d_in[2];
    float* out = (float*)d_out;

    dim3 grid(BATCH * 8 * NHEAD);   // 1024 blocks: (window, head)
    dim3 block(512);                // 8 waves; 2 blocks/CU if VGPR <= 128
    lepe_attn_f16<<<grid, block, 0, stream>>>(qkv, conv_w, conv_b, out);
}